// Round 11
// baseline (164.984 us; speedup 1.0000x reference)
//
#include <hip/hip_runtime.h>

// Problem constants
#define BATCH 2
#define NSEQ 2304       // 48*48
#define DIM 768
#define HEADS 12
#define HD 64
#define M_TOK (BATCH * NSEQ)   // 4608
#define LDSP 72                // padded LDS row stride (bf16 elems)
#define KP 72                  // attn LDS row stride (elems) for K (bf16) and V^T (f16)
#define BH (BATCH * HEADS)     // 24
#define KT_HALF (NSEQ / 64 / 2) // 18 key-tiles per half
#define NKT (DIM / 64)          // 12 k-steps in qkv/proj GEMMs

typedef __attribute__((ext_vector_type(8))) short bf16x8;
typedef __attribute__((ext_vector_type(8))) short short8v;
typedef __attribute__((ext_vector_type(4))) float f32x4;
typedef __fp16 fp16x2 __attribute__((ext_vector_type(2)));
typedef _Float16 half4 __attribute__((ext_vector_type(4)));
typedef _Float16 half8 __attribute__((ext_vector_type(8)));

// softmax scale folded with log2(e): exp(x) = exp2(x * log2e)
#define QSCALE (0.125f * 1.44269504088896f)
#define LOG2_100_D16 0.41524101186092029f   // log2(100)/16

__device__ __forceinline__ short f2bf(float f) {
    union { float f; unsigned u; } v; v.f = f;
    unsigned r = v.u + 0x7fffu + ((v.u >> 16) & 1u);
    return (short)(r >> 16);
}

// ---------------- merged fp32 -> bf16 conversion for x, w_qkv, w_proj ----------------
#define CN1 (M_TOK * DIM / 4)        // 884736
#define CN2 (3 * DIM * DIM / 4)      // 442368
#define CN3 (DIM * DIM / 4)          // 147456
__global__ void cvt_all_kernel(const float* __restrict__ x, const float* __restrict__ wq,
                               const float* __restrict__ wp,
                               short* __restrict__ xb, short* __restrict__ wqb,
                               short* __restrict__ wpb) {
    int i = blockIdx.x * 256 + threadIdx.x;
    const float* src; short* dst; int j;
    if (i < CN1)              { src = x;  dst = xb;  j = i; }
    else if (i < CN1 + CN2)   { src = wq; dst = wqb; j = i - CN1; }
    else                      { src = wp; dst = wpb; j = i - CN1 - CN2; }
    float4 v = reinterpret_cast<const float4*>(src)[j];
    short4 o;
    o.x = f2bf(v.x); o.y = f2bf(v.y); o.z = f2bf(v.z); o.w = f2bf(v.w);
    reinterpret_cast<short4*>(dst)[j] = o;
}

// ---------------- qkv GEMM: 128x128 tile, 8 waves, global_load_lds, XOR-swizzled ----------------
// R10 structure (kept): 512 threads, per-wave 32x64, 64 KB LDS, 2 blocks/CU -> 4 waves/SIMD.
__global__ __launch_bounds__(512) void gemm_qkv_kernel(
    const short* __restrict__ A,    // xb [4608,768]
    const short* __restrict__ Bt,   // wqkvb [2304,768]
    const float* __restrict__ bias, // [2304]
    short* __restrict__ qb, short* __restrict__ kbuf, _Float16* __restrict__ vtb)
{
    __shared__ __align__(16) short At[2][128 * 64];
    __shared__ __align__(16) short Bl[2][128 * 64];
    const int m0 = blockIdx.x * 128, n0 = blockIdx.y * 128;
    const int tid = threadIdx.x, lane = tid & 63, wave = tid >> 6;   // 0..7
    const int quad = lane >> 4, l16 = lane & 15;
    const int wm = (wave >> 1) * 32, wn = (wave & 1) * 64;
    f32x4 acc[2][4] = {};

    // staging: wave w covers rows w*16..w*16+15 (2 issues x 8 rows each).
    // lane l -> row offset lrow=l>>3, LDS block p=l&7 holds source block
    // j = p ^ (row&7) = (l&7)^(l>>3).
    const int lrow = lane >> 3;
    const int jsw = (lane & 7) ^ lrow;
    const short* aBase = &A[(size_t)(m0 + wave * 16 + lrow) * DIM + jsw * 8];
    const short* bBase = &Bt[(size_t)(n0 + wave * 16 + lrow) * DIM + jsw * 8];

    auto stage = [&](int buf, int k0) {
#pragma unroll
        for (int i = 0; i < 2; ++i) {
            __builtin_amdgcn_global_load_lds(
                (const __attribute__((address_space(1))) unsigned int*)(aBase + k0 + i * 8 * DIM),
                (__attribute__((address_space(3))) unsigned int*)&At[buf][(wave * 2 + i) * 512],
                16, 0, 0);
            __builtin_amdgcn_global_load_lds(
                (const __attribute__((address_space(1))) unsigned int*)(bBase + k0 + i * 8 * DIM),
                (__attribute__((address_space(3))) unsigned int*)&Bl[buf][(wave * 2 + i) * 512],
                16, 0, 0);
        }
    };

    stage(0, 0);   // prologue: tile 0 in flight

    const int rx = l16 & 7;   // read-side swizzle key (row&7 == l16&7 for frag rows)
    int cur = 0;
    for (int kt = 0; kt < NKT; ++kt) {
        __syncthreads();   // compiler drains vmcnt(0): buf[cur] complete, buf[cur^1] free
        if (kt + 1 < NKT) stage(cur ^ 1, (kt + 1) * 64);   // async DMA during compute
#pragma unroll
        for (int ks = 0; ks < 2; ++ks) {
            bf16x8 af[2], bf[4];
#pragma unroll
            for (int mt = 0; mt < 2; ++mt) {
                const int R = wm + mt * 16 + l16;
                af[mt] = *reinterpret_cast<const bf16x8*>(
                    &At[cur][R * 64 + (((ks * 4 + quad) ^ rx) * 8)]);
            }
#pragma unroll
            for (int nt = 0; nt < 4; ++nt) {
                const int R = wn + nt * 16 + l16;
                bf[nt] = *reinterpret_cast<const bf16x8*>(
                    &Bl[cur][R * 64 + (((ks * 4 + quad) ^ rx) * 8)]);
            }
#pragma unroll
            for (int mt = 0; mt < 2; ++mt)
#pragma unroll
                for (int nt = 0; nt < 4; ++nt)
                    acc[mt][nt] = __builtin_amdgcn_mfma_f32_16x16x32_bf16(af[mt], bf[nt], acc[mt][nt], 0, 0, 0);
        }
        cur ^= 1;
    }

    const int which = (n0 + wn) / DIM;          // 0=q 1=k 2=v (wave-uniform)
    const int head = ((n0 + wn) % DIM) / HD;
    const int b = m0 / NSEQ;
    const int tokb = m0 % NSEQ + wm;
    if (which == 2) {
#pragma unroll
        for (int mt = 0; mt < 2; ++mt)
#pragma unroll
            for (int nt = 0; nt < 4; ++nt) {
                const int n = n0 + wn + nt * 16 + l16;
                const int d = nt * 16 + l16;
                const float bi = bias[n];
                const int tok0 = tokb + mt * 16 + quad * 4;
                half4 hv;
                hv.x = (_Float16)(acc[mt][nt][0] + bi);
                hv.y = (_Float16)(acc[mt][nt][1] + bi);
                hv.z = (_Float16)(acc[mt][nt][2] + bi);
                hv.w = (_Float16)(acc[mt][nt][3] + bi);
                *reinterpret_cast<half4*>(&vtb[((size_t)(b * HEADS + head) * HD + d) * NSEQ + tok0]) = hv;
            }
    } else {
        // fused RoPE: pairs (d, d+32) = (nt, nt+2); pi = l16
        short* dst = (which == 0) ? qb : kbuf;
        const float qs = (which == 0) ? QSCALE : 1.0f;
        float bi[4];
#pragma unroll
        for (int nt = 0; nt < 4; ++nt) bi[nt] = bias[n0 + wn + nt * 16 + l16];
        const float invp = __builtin_amdgcn_exp2f(-(float)l16 * LOG2_100_D16); // 100^(-l16/16)
#pragma unroll
        for (int mt = 0; mt < 2; ++mt) {
#pragma unroll
            for (int rg = 0; rg < 4; ++rg) {
                const int tok = tokb + mt * 16 + quad * 4 + rg;
                const int yy = tok / 48, xx = tok - yy * 48;
                const float ry = (2.0f * (yy + 0.5f) * (1.0f / 48.0f) - 1.0f) * invp; // revolutions
                const float rx2 = (2.0f * (xx + 0.5f) * (1.0f / 48.0f) - 1.0f) * invp;
                const float sy = __builtin_amdgcn_sinf(ry), cy = __builtin_amdgcn_cosf(ry);
                const float sx = __builtin_amdgcn_sinf(rx2), cx = __builtin_amdgcn_cosf(rx2);
                const float a0 = acc[mt][0][rg] + bi[0];
                const float a1 = acc[mt][1][rg] + bi[1];
                const float a2 = acc[mt][2][rg] + bi[2];
                const float a3 = acc[mt][3][rg] + bi[3];
                short* rp = &dst[((size_t)(b * HEADS + head) * NSEQ + tok) * HD];
                rp[l16]      = f2bf((a0 * cy - a2 * sy) * qs);
                rp[32 + l16] = f2bf((a2 * cy + a0 * sy) * qs);
                rp[16 + l16] = f2bf((a1 * cx - a3 * sx) * qs);
                rp[48 + l16] = f2bf((a3 * cx + a1 * sx) * qs);
            }
        }
    }
}

// ---------------- flash attention: 8 waves x 32 q-rows, key-split x2, XCD-swizzled ----------------
// R6 structure (kept): <=128-reg tier -> 4 waves/SIMD; 512-thread blocks, 256 rows.
// K/V LDS layouts conflict-uniform b128 (R4).
__global__ __launch_bounds__(512, 4) void attn_kernel(
    const short* __restrict__ qb, const short* __restrict__ kb,
    const _Float16* __restrict__ vtb, _Float16* __restrict__ opart,
    float* __restrict__ lpart)
{
    __shared__ __align__(16) short    Kt[2][64 * KP];   // [key][d]        bf16
    __shared__ __align__(16) _Float16 Vt[2][64 * KP];   // [d][tok-perm]   f16
    const int wg = blockIdx.x;
    const int xcd = wg & 7;
    const int slot = wg >> 3;              // 0..53
    const int slab = xcd * 6 + slot / 9;   // 0..47 (all 9 q-tiles of a slab on one XCD)
    const int qt = slot % 9;
    const int kh = slab & 1;
    const int bh = slab >> 1;
    const int tid = threadIdx.x, lane = tid & 63, wave = tid >> 6;   // wave 0..7
    const int quad = lane >> 4, l16 = lane & 15;
    const int qrow0 = qt * 256 + wave * 32;
    const short* qbase = qb + (size_t)bh * NSEQ * HD;
    const short* kbase = kb + (size_t)bh * NSEQ * HD;
    const _Float16* vbase = vtb + (size_t)bh * HD * NSEQ;

    bf16x8 qf[2][2];
#pragma unroll
    for (int mt = 0; mt < 2; ++mt)
#pragma unroll
        for (int ks = 0; ks < 2; ++ks)
            qf[mt][ks] = *reinterpret_cast<const bf16x8*>(
                &qbase[(size_t)(qrow0 + mt * 16 + l16) * HD + ks * 32 + quad * 8]);

    half8 ones8;
#pragma unroll
    for (int j = 0; j < 8; ++j) ones8[j] = (_Float16)1.0f;

    f32x4 oacc[2][4] = {};
    f32x4 lacc[2] = {};

    // staging (512 threads, one uint4 each):
    //   K: row rk = tid>>3, 8 shorts at ck = (tid&7)*8
    //   V: d-row rv = tid>>3, 8 tokens T = 8*(tid&7); permuted dest
    //      p0 = 32*(w>>2) + 16*(w&1) + 4*((w>>1)&1)  [uint2 at p0, p0+8]
    const int rk = tid >> 3, ck = (tid & 7) * 8;
    const int wv = tid & 7;
    const int vdst = rk * KP + 32 * (wv >> 2) + 16 * (wv & 1) + 4 * ((wv >> 1) & 1);
    const int t0 = kh * (NSEQ / 2);
    const short* kp = kbase + (size_t)(t0 + rk) * HD + ck;
    const _Float16* vp = vbase + (size_t)rk * NSEQ + t0 + wv * 8;

    // prologue: stage first tile into buffer 0
    {
        uint4 k0 = *reinterpret_cast<const uint4*>(kp);
        uint4 v0 = *reinterpret_cast<const uint4*>(vp);
        *reinterpret_cast<uint4*>(&Kt[0][rk * KP + ck]) = k0;
        _Float16* vb = &Vt[0][vdst];
        *reinterpret_cast<uint2*>(vb + 0) = make_uint2(v0.x, v0.y);
        *reinterpret_cast<uint2*>(vb + 8) = make_uint2(v0.z, v0.w);
        kp += 64 * HD;
        vp += 64;
    }

    int cur = 0;
    for (int kt = 0; kt < KT_HALF; ++kt) {
        __syncthreads();   // buf[cur] visible; readers of buf[cur^1] done
        uint4 k0, v0;
        const bool pre = (kt + 1 < KT_HALF);
        if (pre) {   // issue next-tile loads; latency hides under this tile's compute
            k0 = *reinterpret_cast<const uint4*>(kp);
            v0 = *reinterpret_cast<const uint4*>(vp);
            kp += 64 * HD;
            vp += 64;
        }

        // hoist K and V^T fragments once, reuse over 2 m-tiles (all b128, conflict-uniform)
        bf16x8 kf[2][4];
#pragma unroll
        for (int ks = 0; ks < 2; ++ks)
#pragma unroll
            for (int nt = 0; nt < 4; ++nt)
                kf[ks][nt] = *reinterpret_cast<const bf16x8*>(
                    &Kt[cur][(nt * 16 + l16) * KP + ks * 32 + quad * 8]);
        half8 vf8[2][4];
#pragma unroll
        for (int n2 = 0; n2 < 2; ++n2)
#pragma unroll
            for (int dt = 0; dt < 4; ++dt)
                vf8[n2][dt] = *reinterpret_cast<const half8*>(
                    &Vt[cur][(dt * 16 + l16) * KP + 32 * n2 + 8 * quad]);

#pragma unroll
        for (int mt = 0; mt < 2; ++mt) {
            // S^T = K Q^T for this 16-row m-tile
            f32x4 sacc[4] = {};
#pragma unroll
            for (int ks = 0; ks < 2; ++ks)
#pragma unroll
                for (int nt = 0; nt < 4; ++nt)
                    sacc[nt] = __builtin_amdgcn_mfma_f32_16x16x32_bf16(
                        kf[ks][nt], qf[mt][ks], sacc[nt], 0, 0, 0);

            // P = exp2(S^T) -> K=32 f16 A-fragments (key-permuted, matches vf8)
            half8 pf8[2];
#pragma unroll
            for (int n2 = 0; n2 < 2; ++n2) {
                fp16x2 w0 = __builtin_amdgcn_cvt_pkrtz(
                    __builtin_amdgcn_exp2f(sacc[2 * n2][0]),
                    __builtin_amdgcn_exp2f(sacc[2 * n2][1]));
                fp16x2 w1 = __builtin_amdgcn_cvt_pkrtz(
                    __builtin_amdgcn_exp2f(sacc[2 * n2][2]),
                    __builtin_amdgcn_exp2f(sacc[2 * n2][3]));
                fp16x2 w2 = __builtin_amdgcn_cvt_pkrtz(
                    __builtin_amdgcn_exp2f(sacc[2 * n2 + 1][0]),
                    __builtin_amdgcn_exp2f(sacc[2 * n2 + 1][1]));
                fp16x2 w3 = __builtin_amdgcn_cvt_pkrtz(
                    __builtin_amdgcn_exp2f(sacc[2 * n2 + 1][2]),
                    __builtin_amdgcn_exp2f(sacc[2 * n2 + 1][3]));
                half8 p;
                p[0] = (_Float16)w0.x; p[1] = (_Float16)w0.y;
                p[2] = (_Float16)w1.x; p[3] = (_Float16)w1.y;
                p[4] = (_Float16)w2.x; p[5] = (_Float16)w2.y;
                p[6] = (_Float16)w3.x; p[7] = (_Float16)w3.y;
                pf8[n2] = p;
            }

            // l += P * ones ; O += P V   (K=32 f16 MFMAs)
#pragma unroll
            for (int n2 = 0; n2 < 2; ++n2)
                lacc[mt] = __builtin_amdgcn_mfma_f32_16x16x32_f16(
                    pf8[n2], ones8, lacc[mt], 0, 0, 0);
#pragma unroll
            for (int n2 = 0; n2 < 2; ++n2)
#pragma unroll
                for (int dt = 0; dt < 4; ++dt)
                    oacc[mt][dt] = __builtin_amdgcn_mfma_f32_16x16x32_f16(
                        pf8[n2], vf8[n2][dt], oacc[mt][dt], 0, 0, 0);
        }

        if (pre) {   // stage next tile; vmcnt wait lands after the tile's compute
            *reinterpret_cast<uint4*>(&Kt[cur ^ 1][rk * KP + ck]) = k0;
            _Float16* vb = &Vt[cur ^ 1][vdst];
            *reinterpret_cast<uint2*>(vb + 0) = make_uint2(v0.x, v0.y);
            *reinterpret_cast<uint2*>(vb + 8) = make_uint2(v0.z, v0.w);
        }
        cur ^= 1;
    }

    // store UNNORMALIZED partials
    _Float16* ob2 = opart + (size_t)(kh * BH + bh) * NSEQ * HD;
    float* lp2 = lpart + (size_t)(kh * BH + bh) * NSEQ;
#pragma unroll
    for (int mt = 0; mt < 2; ++mt) {
#pragma unroll
        for (int dt = 0; dt < 4; ++dt)
#pragma unroll
            for (int rg = 0; rg < 4; ++rg) {
                int row = qrow0 + mt * 16 + quad * 4 + rg;
                ob2[(size_t)row * HD + dt * 16 + l16] = (_Float16)oacc[mt][dt][rg];
            }
        if (l16 == 0) {
#pragma unroll
            for (int rg = 0; rg < 4; ++rg)
                lp2[qrow0 + mt * 16 + quad * 4 + rg] = lacc[mt][rg];
        }
    }
}

// ---------------- proj GEMM v2: 128x64 tile, 8 waves, fused combine, 1 barrier/iter ----------------
// R11: proj was the last un-modernized kernel (64x64 tile, 4 waves, 2 barriers/iter,
// no double-buffer) - the hidden ~45-55us under the poison fills. Now: 512 threads,
// per-wave 32x32 output, double-buffered LDS, ONE barrier/iter. B (wproj) staged via
// global_load_lds with the proven XOR pre-swizzle (0 conflicts); A (combined+
// normalized partials) reg-loaded right after the barrier, combined and ds_written
// (pad-72) after compute - a full compute phase of load latency hiding. LDS 52 KB
// -> 3 blocks/CU. Grid (36,12)=432 blocks.
__global__ __launch_bounds__(512) void gemm_proj_kernel(
    const _Float16* __restrict__ op,  // [2][bh][row][d] f16 partials
    const float* __restrict__ lp,     // [2][bh][row] f32 partials
    const short* __restrict__ Bt,     // wprojb [768,768]
    const float* __restrict__ bias,   // [768]
    float* __restrict__ out)
{
    __shared__ __align__(16) short At[2][128 * LDSP];   // combined A, pad-72
    __shared__ __align__(16) short Bl[2][64 * 64];      // wproj, linear + XOR swizzle
    const int m0 = blockIdx.x * 128, n0 = blockIdx.y * 64;
    const int tid = threadIdx.x, lane = tid & 63, wave = tid >> 6;   // 0..7
    const int quad = lane >> 4, l16 = lane & 15;
    const int wm = (wave >> 1) * 32, wn = (wave & 1) * 32;
    const int b = m0 / NSEQ;
    const int ra = tid >> 2, ca = (tid & 3) * 16;   // A-combine: 4 threads/row, 16 cols
    const int tok = m0 % NSEQ + ra;
    f32x4 acc[2][2] = {};

    // B staging via global_load_lds: wave w covers rows w*8..w*8+7 (512 shorts).
    // lane l: row offset l>>3, LDS block p=l&7 holds source block j=(l&7)^(l>>3).
    const int lrow = lane >> 3;
    const int jsw = (lane & 7) ^ lrow;
    const short* bBase = &Bt[(size_t)(n0 + wave * 8 + lrow) * DIM + jsw * 8];
    auto stageB = [&](int buf, int k0) {
        __builtin_amdgcn_global_load_lds(
            (const __attribute__((address_space(1))) unsigned int*)(bBase + k0),
            (__attribute__((address_space(3))) unsigned int*)&Bl[buf][wave * 512],
            16, 0, 0);
    };

    // A combine state (16 VGPRs staging)
    half8 a0, a1, a2, a3;
    float ls;
    auto loadA = [&](int h) {   // h = head = k-tile index
        const size_t pb = (size_t)(b * HEADS + h) * NSEQ + tok;
        const half8* o0 = reinterpret_cast<const half8*>(&op[pb * HD + ca]);
        const half8* o1 = reinterpret_cast<const half8*>(&op[(size_t)BH * NSEQ * HD + pb * HD + ca]);
        a0 = o0[0]; a1 = o0[1];
        a2 = o1[0]; a3 = o1[1];
        ls = lp[pb] + lp[(size_t)BH * NSEQ + pb];
    };
    auto storeA = [&](int buf) {
        const float inv = __builtin_amdgcn_rcpf(ls);
        short8v s0, s1;
#pragma unroll
        for (int j = 0; j < 8; ++j) {
            s0[j] = f2bf(((float)a0[j] + (float)a2[j]) * inv);
            s1[j] = f2bf(((float)a1[j] + (float)a3[j]) * inv);
        }
        *reinterpret_cast<short8v*>(&At[buf][ra * LDSP + ca]) = s0;
        *reinterpret_cast<short8v*>(&At[buf][ra * LDSP + ca + 8]) = s1;
    };

    // prologue: tile 0 (A combined to LDS, B DMA in flight)
    loadA(0);
    stageB(0, 0);
    storeA(0);

    const int rx = l16 & 7;
    int cur = 0;
    for (int t = 0; t < NKT; ++t) {
        __syncthreads();   // drains vmcnt(0): Bl[cur] complete; At[cur] writes visible
        const bool pre = (t + 1 < NKT);
        if (pre) {
            stageB(cur ^ 1, (t + 1) * 64);   // async DMA during compute
            loadA(t + 1);                    // A-part loads in flight during compute
        }
#pragma unroll
        for (int ks = 0; ks < 2; ++ks) {
            bf16x8 af[2], bf[2];
#pragma unroll
            for (int mt = 0; mt < 2; ++mt)
                af[mt] = *reinterpret_cast<const bf16x8*>(
                    &At[cur][(wm + mt * 16 + l16) * LDSP + ks * 32 + quad * 8]);
#pragma unroll
            for (int nt = 0; nt < 2; ++nt) {
                const int R = wn + nt * 16 + l16;
                bf[nt] = *reinterpret_cast<const bf16x8*>(
                    &Bl[cur][R * 64 + (((ks * 4 + quad) ^ rx) * 8)]);
            }
#pragma unroll
            for (int mt = 0; mt < 2; ++mt)
#pragma unroll
                for (int nt = 0; nt < 2; ++nt)
                    acc[mt][nt] = __builtin_amdgcn_mfma_f32_16x16x32_bf16(af[mt], bf[nt], acc[mt][nt], 0, 0, 0);
        }
        if (pre) storeA(cur ^ 1);   // combine waits on loads issued above (compute-phase latency)
        cur ^= 1;
    }

#pragma unroll
    for (int mt = 0; mt < 2; ++mt)
#pragma unroll
        for (int nt = 0; nt < 2; ++nt) {
            const int n = n0 + wn + nt * 16 + l16;
            const float bi = bias[n];
#pragma unroll
            for (int rg = 0; rg < 4; ++rg) {
                const int m = m0 + wm + mt * 16 + quad * 4 + rg;
                out[(size_t)m * DIM + n] = acc[mt][nt][rg] + bi;
            }
        }
}

extern "C" void kernel_launch(void* const* d_in, const int* in_sizes, int n_in,
                              void* d_out, int out_size, void* d_ws, size_t ws_size,
                              hipStream_t stream) {
    const float* x      = (const float*)d_in[0];
    const float* w_qkv  = (const float*)d_in[1];
    const float* b_qkv  = (const float*)d_in[2];
    const float* w_proj = (const float*)d_in[3];
    const float* b_proj = (const float*)d_in[4];
    float* out = (float*)d_out;

    short* xb     = (short*)d_ws;                         // 4608*768
    short* wqkvb  = xb + (size_t)M_TOK * DIM;             // 2304*768
    short* wprojb = wqkvb + (size_t)3 * DIM * DIM;        // 768*768
    short* qb     = wprojb + (size_t)DIM * DIM;           // 24*2304*64 bf16
    short* kb     = qb + (size_t)BH * NSEQ * HD;
    short* vtb    = kb + (size_t)BH * NSEQ * HD;          // f16 [bh,d,tok]
    short* opart  = vtb + (size_t)BH * NSEQ * HD;         // f16 [2,bh,row,d]
    float* lpart  = (float*)(opart + (size_t)2 * BH * NSEQ * HD); // f32 [2,bh,row]

    // merged converts (1 kernel)
    cvt_all_kernel<<<(CN1 + CN2 + CN3) / 256, 256, 0, stream>>>(
        x, w_qkv, w_proj, xb, wqkvb, wprojb);

    // qkv GEMM + bias + RoPE + QSCALE + scatter (8 waves, global_load_lds staging)
    dim3 g1(M_TOK / 128, 3 * DIM / 128);
    gemm_qkv_kernel<<<g1, 512, 0, stream>>>(xb, wqkvb, b_qkv, qb, kb, (_Float16*)vtb);

    // attention partials (key-split x2), 8 waves x 32 q-rows, XCD-swizzled 1D grid
    attn_kernel<<<dim3(9 * 2 * BH), 512, 0, stream>>>(qb, kb, (const _Float16*)vtb,
                                                      (_Float16*)opart, lpart);

    // proj GEMM v2 with fused combine+normalize (8 waves, 1 barrier/iter)
    gemm_proj_kernel<<<dim3(M_TOK / 128, DIM / 64), 512, 0, stream>>>(
        (const _Float16*)opart, lpart, wprojb, b_proj, out);
}

// Round 12
// 162.232 us; speedup vs baseline: 1.0170x; 1.0170x over previous
//
#include <hip/hip_runtime.h>

// Problem constants
#define BATCH 2
#define NSEQ 2304       // 48*48
#define DIM 768
#define HEADS 12
#define HD 64
#define M_TOK (BATCH * NSEQ)   // 4608
#define LDSP 72                // padded LDS row stride (bf16 elems)
#define KP 72                  // attn LDS row stride (elems) for K (bf16) and V^T (f16)
#define BH (BATCH * HEADS)     // 24
#define KT_HALF (NSEQ / 64 / 2) // 18 key-tiles per half
#define NKT (DIM / 64)          // 12 k-steps in qkv/proj GEMMs

typedef __attribute__((ext_vector_type(8))) short bf16x8;
typedef __attribute__((ext_vector_type(8))) short short8v;
typedef __attribute__((ext_vector_type(4))) float f32x4;
typedef __fp16 fp16x2 __attribute__((ext_vector_type(2)));
typedef _Float16 half4 __attribute__((ext_vector_type(4)));
typedef _Float16 half8 __attribute__((ext_vector_type(8)));

// softmax scale folded with log2(e): exp(x) = exp2(x * log2e)
#define QSCALE (0.125f * 1.44269504088896f)
#define LOG2_100_D16 0.41524101186092029f   // log2(100)/16

__device__ __forceinline__ short f2bf(float f) {
    union { float f; unsigned u; } v; v.f = f;
    unsigned r = v.u + 0x7fffu + ((v.u >> 16) & 1u);
    return (short)(r >> 16);
}

// ---------------- merged fp32 -> bf16 conversion for x, w_qkv, w_proj ----------------
#define CN1 (M_TOK * DIM / 4)        // 884736
#define CN2 (3 * DIM * DIM / 4)      // 442368
#define CN3 (DIM * DIM / 4)          // 147456
__global__ void cvt_all_kernel(const float* __restrict__ x, const float* __restrict__ wq,
                               const float* __restrict__ wp,
                               short* __restrict__ xb, short* __restrict__ wqb,
                               short* __restrict__ wpb) {
    int i = blockIdx.x * 256 + threadIdx.x;
    const float* src; short* dst; int j;
    if (i < CN1)              { src = x;  dst = xb;  j = i; }
    else if (i < CN1 + CN2)   { src = wq; dst = wqb; j = i - CN1; }
    else                      { src = wp; dst = wpb; j = i - CN1 - CN2; }
    float4 v = reinterpret_cast<const float4*>(src)[j];
    short4 o;
    o.x = f2bf(v.x); o.y = f2bf(v.y); o.z = f2bf(v.z); o.w = f2bf(v.w);
    reinterpret_cast<short4*>(dst)[j] = o;
}

// ---------------- qkv GEMM: 128x128 tile, 8 waves, 3-buffer counted-vmcnt pipeline ----------------
// R12: R6/R9/R10 all ~50us regardless of staging mechanism -> the vmcnt(0) drain
// before every __syncthreads serialized DMA latency with compute (m97-ceiling
// mechanism). T4 fix (m218: counted-vs-drain0 +38-73%): 3 LDS buffers, tile t's
// loads issued at iter t-2, and before computing t only "s_waitcnt vmcnt(4)" (my 4
// tile-t loads done; tile-t+1's 4 stay IN FLIGHT across the barrier) + raw s_barrier
// + sched_barrier(0) (rule #18). stage(t+2) overwrites buf[(t-1)%3] - safe, issued
// after the barrier where all waves finished reading it. Loop has no other VMEM ops
// so vmcnt counts are exact. LDS 96 KB -> 1 block/CU (pipeline depth replaces TLP,
// cf. m201 template also 1 block/CU).
__global__ __launch_bounds__(512) void gemm_qkv_kernel(
    const short* __restrict__ A,    // xb [4608,768]
    const short* __restrict__ Bt,   // wqkvb [2304,768]
    const float* __restrict__ bias, // [2304]
    short* __restrict__ qb, short* __restrict__ kbuf, _Float16* __restrict__ vtb)
{
    __shared__ __align__(16) short At[3][128 * 64];
    __shared__ __align__(16) short Bl[3][128 * 64];
    const int m0 = blockIdx.x * 128, n0 = blockIdx.y * 128;
    const int tid = threadIdx.x, lane = tid & 63, wave = tid >> 6;   // 0..7
    const int quad = lane >> 4, l16 = lane & 15;
    const int wm = (wave >> 1) * 32, wn = (wave & 1) * 64;
    f32x4 acc[2][4] = {};

    // staging: wave w covers rows w*16..w*16+15 (2 issues x 8 rows each side).
    // lane l -> row offset lrow=l>>3, LDS block p=l&7 holds source block
    // j = p ^ (row&7) = (l&7)^(l>>3).
    const int lrow = lane >> 3;
    const int jsw = (lane & 7) ^ lrow;
    const short* aBase = &A[(size_t)(m0 + wave * 16 + lrow) * DIM + jsw * 8];
    const short* bBase = &Bt[(size_t)(n0 + wave * 16 + lrow) * DIM + jsw * 8];

    auto stage = [&](int buf, int k0) {   // 4 gload_lds per wave
#pragma unroll
        for (int i = 0; i < 2; ++i) {
            __builtin_amdgcn_global_load_lds(
                (const __attribute__((address_space(1))) unsigned int*)(aBase + k0 + i * 8 * DIM),
                (__attribute__((address_space(3))) unsigned int*)&At[buf][(wave * 2 + i) * 512],
                16, 0, 0);
            __builtin_amdgcn_global_load_lds(
                (const __attribute__((address_space(1))) unsigned int*)(bBase + k0 + i * 8 * DIM),
                (__attribute__((address_space(3))) unsigned int*)&Bl[buf][(wave * 2 + i) * 512],
                16, 0, 0);
        }
    };

    // prologue: tiles 0 and 1 in flight (8 loads/wave outstanding)
    stage(0, 0);
    stage(1, 64);

    const int rx = l16 & 7;   // read-side swizzle key (row&7 == l16&7 for frag rows)
    int cur = 0;              // buffer index = kt % 3
    for (int kt = 0; kt < NKT; ++kt) {
        // wait: my 4 tile-kt loads complete; tile-(kt+1)'s 4 may remain in flight
        if (kt < NKT - 1) asm volatile("s_waitcnt vmcnt(4)" ::: "memory");
        else              asm volatile("s_waitcnt vmcnt(0)" ::: "memory");
        __builtin_amdgcn_s_barrier();          // all waves' tile-kt data visible
        __builtin_amdgcn_sched_barrier(0);     // nothing crosses (rule #18)
        if (kt + 2 < NKT) {
            const int nb = (cur + 2 >= 3) ? cur - 1 : cur + 2;
            stage(nb, (kt + 2) * 64);          // overwrites buf[(kt-1)%3]: readers done
        }
#pragma unroll
        for (int ks = 0; ks < 2; ++ks) {
            bf16x8 af[2], bf[4];
#pragma unroll
            for (int mt = 0; mt < 2; ++mt) {
                const int R = wm + mt * 16 + l16;
                af[mt] = *reinterpret_cast<const bf16x8*>(
                    &At[cur][R * 64 + (((ks * 4 + quad) ^ rx) * 8)]);
            }
#pragma unroll
            for (int nt = 0; nt < 4; ++nt) {
                const int R = wn + nt * 16 + l16;
                bf[nt] = *reinterpret_cast<const bf16x8*>(
                    &Bl[cur][R * 64 + (((ks * 4 + quad) ^ rx) * 8)]);
            }
#pragma unroll
            for (int mt = 0; mt < 2; ++mt)
#pragma unroll
                for (int nt = 0; nt < 4; ++nt)
                    acc[mt][nt] = __builtin_amdgcn_mfma_f32_16x16x32_bf16(af[mt], bf[nt], acc[mt][nt], 0, 0, 0);
        }
        __builtin_amdgcn_sched_barrier(0);     // keep iteration regions ordered
        cur = (cur + 1 >= 3) ? 0 : cur + 1;
    }

    const int which = (n0 + wn) / DIM;          // 0=q 1=k 2=v (wave-uniform)
    const int head = ((n0 + wn) % DIM) / HD;
    const int b = m0 / NSEQ;
    const int tokb = m0 % NSEQ + wm;
    if (which == 2) {
#pragma unroll
        for (int mt = 0; mt < 2; ++mt)
#pragma unroll
            for (int nt = 0; nt < 4; ++nt) {
                const int n = n0 + wn + nt * 16 + l16;
                const int d = nt * 16 + l16;
                const float bi = bias[n];
                const int tok0 = tokb + mt * 16 + quad * 4;
                half4 hv;
                hv.x = (_Float16)(acc[mt][nt][0] + bi);
                hv.y = (_Float16)(acc[mt][nt][1] + bi);
                hv.z = (_Float16)(acc[mt][nt][2] + bi);
                hv.w = (_Float16)(acc[mt][nt][3] + bi);
                *reinterpret_cast<half4*>(&vtb[((size_t)(b * HEADS + head) * HD + d) * NSEQ + tok0]) = hv;
            }
    } else {
        // fused RoPE: pairs (d, d+32) = (nt, nt+2); pi = l16
        short* dst = (which == 0) ? qb : kbuf;
        const float qs = (which == 0) ? QSCALE : 1.0f;
        float bi[4];
#pragma unroll
        for (int nt = 0; nt < 4; ++nt) bi[nt] = bias[n0 + wn + nt * 16 + l16];
        const float invp = __builtin_amdgcn_exp2f(-(float)l16 * LOG2_100_D16); // 100^(-l16/16)
#pragma unroll
        for (int mt = 0; mt < 2; ++mt) {
#pragma unroll
            for (int rg = 0; rg < 4; ++rg) {
                const int tok = tokb + mt * 16 + quad * 4 + rg;
                const int yy = tok / 48, xx = tok - yy * 48;
                const float ry = (2.0f * (yy + 0.5f) * (1.0f / 48.0f) - 1.0f) * invp; // revolutions
                const float rx2 = (2.0f * (xx + 0.5f) * (1.0f / 48.0f) - 1.0f) * invp;
                const float sy = __builtin_amdgcn_sinf(ry), cy = __builtin_amdgcn_cosf(ry);
                const float sx = __builtin_amdgcn_sinf(rx2), cx = __builtin_amdgcn_cosf(rx2);
                const float a0 = acc[mt][0][rg] + bi[0];
                const float a1 = acc[mt][1][rg] + bi[1];
                const float a2 = acc[mt][2][rg] + bi[2];
                const float a3 = acc[mt][3][rg] + bi[3];
                short* rp = &dst[((size_t)(b * HEADS + head) * NSEQ + tok) * HD];
                rp[l16]      = f2bf((a0 * cy - a2 * sy) * qs);
                rp[32 + l16] = f2bf((a2 * cy + a0 * sy) * qs);
                rp[16 + l16] = f2bf((a1 * cx - a3 * sx) * qs);
                rp[48 + l16] = f2bf((a3 * cx + a1 * sx) * qs);
            }
        }
    }
}

// ---------------- flash attention: 8 waves x 32 q-rows, key-split x2, XCD-swizzled ----------------
// R6 structure (kept): <=128-reg tier -> 4 waves/SIMD; 512-thread blocks, 256 rows.
// K/V LDS layouts conflict-uniform b128 (R4).
__global__ __launch_bounds__(512, 4) void attn_kernel(
    const short* __restrict__ qb, const short* __restrict__ kb,
    const _Float16* __restrict__ vtb, _Float16* __restrict__ opart,
    float* __restrict__ lpart)
{
    __shared__ __align__(16) short    Kt[2][64 * KP];   // [key][d]        bf16
    __shared__ __align__(16) _Float16 Vt[2][64 * KP];   // [d][tok-perm]   f16
    const int wg = blockIdx.x;
    const int xcd = wg & 7;
    const int slot = wg >> 3;              // 0..53
    const int slab = xcd * 6 + slot / 9;   // 0..47 (all 9 q-tiles of a slab on one XCD)
    const int qt = slot % 9;
    const int kh = slab & 1;
    const int bh = slab >> 1;
    const int tid = threadIdx.x, lane = tid & 63, wave = tid >> 6;   // wave 0..7
    const int quad = lane >> 4, l16 = lane & 15;
    const int qrow0 = qt * 256 + wave * 32;
    const short* qbase = qb + (size_t)bh * NSEQ * HD;
    const short* kbase = kb + (size_t)bh * NSEQ * HD;
    const _Float16* vbase = vtb + (size_t)bh * HD * NSEQ;

    bf16x8 qf[2][2];
#pragma unroll
    for (int mt = 0; mt < 2; ++mt)
#pragma unroll
        for (int ks = 0; ks < 2; ++ks)
            qf[mt][ks] = *reinterpret_cast<const bf16x8*>(
                &qbase[(size_t)(qrow0 + mt * 16 + l16) * HD + ks * 32 + quad * 8]);

    half8 ones8;
#pragma unroll
    for (int j = 0; j < 8; ++j) ones8[j] = (_Float16)1.0f;

    f32x4 oacc[2][4] = {};
    f32x4 lacc[2] = {};

    // staging (512 threads, one uint4 each):
    //   K: row rk = tid>>3, 8 shorts at ck = (tid&7)*8
    //   V: d-row rv = tid>>3, 8 tokens T = 8*(tid&7); permuted dest
    //      p0 = 32*(w>>2) + 16*(w&1) + 4*((w>>1)&1)  [uint2 at p0, p0+8]
    const int rk = tid >> 3, ck = (tid & 7) * 8;
    const int wv = tid & 7;
    const int vdst = rk * KP + 32 * (wv >> 2) + 16 * (wv & 1) + 4 * ((wv >> 1) & 1);
    const int t0 = kh * (NSEQ / 2);
    const short* kp = kbase + (size_t)(t0 + rk) * HD + ck;
    const _Float16* vp = vbase + (size_t)rk * NSEQ + t0 + wv * 8;

    // prologue: stage first tile into buffer 0
    {
        uint4 k0 = *reinterpret_cast<const uint4*>(kp);
        uint4 v0 = *reinterpret_cast<const uint4*>(vp);
        *reinterpret_cast<uint4*>(&Kt[0][rk * KP + ck]) = k0;
        _Float16* vb = &Vt[0][vdst];
        *reinterpret_cast<uint2*>(vb + 0) = make_uint2(v0.x, v0.y);
        *reinterpret_cast<uint2*>(vb + 8) = make_uint2(v0.z, v0.w);
        kp += 64 * HD;
        vp += 64;
    }

    int cur = 0;
    for (int kt = 0; kt < KT_HALF; ++kt) {
        __syncthreads();   // buf[cur] visible; readers of buf[cur^1] done
        uint4 k0, v0;
        const bool pre = (kt + 1 < KT_HALF);
        if (pre) {   // issue next-tile loads; latency hides under this tile's compute
            k0 = *reinterpret_cast<const uint4*>(kp);
            v0 = *reinterpret_cast<const uint4*>(vp);
            kp += 64 * HD;
            vp += 64;
        }

        // hoist K and V^T fragments once, reuse over 2 m-tiles (all b128, conflict-uniform)
        bf16x8 kf[2][4];
#pragma unroll
        for (int ks = 0; ks < 2; ++ks)
#pragma unroll
            for (int nt = 0; nt < 4; ++nt)
                kf[ks][nt] = *reinterpret_cast<const bf16x8*>(
                    &Kt[cur][(nt * 16 + l16) * KP + ks * 32 + quad * 8]);
        half8 vf8[2][4];
#pragma unroll
        for (int n2 = 0; n2 < 2; ++n2)
#pragma unroll
            for (int dt = 0; dt < 4; ++dt)
                vf8[n2][dt] = *reinterpret_cast<const half8*>(
                    &Vt[cur][(dt * 16 + l16) * KP + 32 * n2 + 8 * quad]);

#pragma unroll
        for (int mt = 0; mt < 2; ++mt) {
            // S^T = K Q^T for this 16-row m-tile
            f32x4 sacc[4] = {};
#pragma unroll
            for (int ks = 0; ks < 2; ++ks)
#pragma unroll
                for (int nt = 0; nt < 4; ++nt)
                    sacc[nt] = __builtin_amdgcn_mfma_f32_16x16x32_bf16(
                        kf[ks][nt], qf[mt][ks], sacc[nt], 0, 0, 0);

            // P = exp2(S^T) -> K=32 f16 A-fragments (key-permuted, matches vf8)
            half8 pf8[2];
#pragma unroll
            for (int n2 = 0; n2 < 2; ++n2) {
                fp16x2 w0 = __builtin_amdgcn_cvt_pkrtz(
                    __builtin_amdgcn_exp2f(sacc[2 * n2][0]),
                    __builtin_amdgcn_exp2f(sacc[2 * n2][1]));
                fp16x2 w1 = __builtin_amdgcn_cvt_pkrtz(
                    __builtin_amdgcn_exp2f(sacc[2 * n2][2]),
                    __builtin_amdgcn_exp2f(sacc[2 * n2][3]));
                fp16x2 w2 = __builtin_amdgcn_cvt_pkrtz(
                    __builtin_amdgcn_exp2f(sacc[2 * n2 + 1][0]),
                    __builtin_amdgcn_exp2f(sacc[2 * n2 + 1][1]));
                fp16x2 w3 = __builtin_amdgcn_cvt_pkrtz(
                    __builtin_amdgcn_exp2f(sacc[2 * n2 + 1][2]),
                    __builtin_amdgcn_exp2f(sacc[2 * n2 + 1][3]));
                half8 p;
                p[0] = (_Float16)w0.x; p[1] = (_Float16)w0.y;
                p[2] = (_Float16)w1.x; p[3] = (_Float16)w1.y;
                p[4] = (_Float16)w2.x; p[5] = (_Float16)w2.y;
                p[6] = (_Float16)w3.x; p[7] = (_Float16)w3.y;
                pf8[n2] = p;
            }

            // l += P * ones ; O += P V   (K=32 f16 MFMAs)
#pragma unroll
            for (int n2 = 0; n2 < 2; ++n2)
                lacc[mt] = __builtin_amdgcn_mfma_f32_16x16x32_f16(
                    pf8[n2], ones8, lacc[mt], 0, 0, 0);
#pragma unroll
            for (int n2 = 0; n2 < 2; ++n2)
#pragma unroll
                for (int dt = 0; dt < 4; ++dt)
                    oacc[mt][dt] = __builtin_amdgcn_mfma_f32_16x16x32_f16(
                        pf8[n2], vf8[n2][dt], oacc[mt][dt], 0, 0, 0);
        }

        if (pre) {   // stage next tile; vmcnt wait lands after the tile's compute
            *reinterpret_cast<uint4*>(&Kt[cur ^ 1][rk * KP + ck]) = k0;
            _Float16* vb = &Vt[cur ^ 1][vdst];
            *reinterpret_cast<uint2*>(vb + 0) = make_uint2(v0.x, v0.y);
            *reinterpret_cast<uint2*>(vb + 8) = make_uint2(v0.z, v0.w);
        }
        cur ^= 1;
    }

    // store UNNORMALIZED partials
    _Float16* ob2 = opart + (size_t)(kh * BH + bh) * NSEQ * HD;
    float* lp2 = lpart + (size_t)(kh * BH + bh) * NSEQ;
#pragma unroll
    for (int mt = 0; mt < 2; ++mt) {
#pragma unroll
        for (int dt = 0; dt < 4; ++dt)
#pragma unroll
            for (int rg = 0; rg < 4; ++rg) {
                int row = qrow0 + mt * 16 + quad * 4 + rg;
                ob2[(size_t)row * HD + dt * 16 + l16] = (_Float16)oacc[mt][dt][rg];
            }
        if (l16 == 0) {
#pragma unroll
            for (int rg = 0; rg < 4; ++rg)
                lp2[qrow0 + mt * 16 + quad * 4 + rg] = lacc[mt][rg];
        }
    }
}

// ---------------- proj GEMM v2: 128x64 tile, 8 waves, fused combine, 1 barrier/iter ----------------
// R11 structure (kept): 512 threads, per-wave 32x32, double-buffered, B via
// global_load_lds + XOR swizzle, A combine reg-loaded during compute phase.
__global__ __launch_bounds__(512) void gemm_proj_kernel(
    const _Float16* __restrict__ op,  // [2][bh][row][d] f16 partials
    const float* __restrict__ lp,     // [2][bh][row] f32 partials
    const short* __restrict__ Bt,     // wprojb [768,768]
    const float* __restrict__ bias,   // [768]
    float* __restrict__ out)
{
    __shared__ __align__(16) short At[2][128 * LDSP];   // combined A, pad-72
    __shared__ __align__(16) short Bl[2][64 * 64];      // wproj, linear + XOR swizzle
    const int m0 = blockIdx.x * 128, n0 = blockIdx.y * 64;
    const int tid = threadIdx.x, lane = tid & 63, wave = tid >> 6;   // 0..7
    const int quad = lane >> 4, l16 = lane & 15;
    const int wm = (wave >> 1) * 32, wn = (wave & 1) * 32;
    const int b = m0 / NSEQ;
    const int ra = tid >> 2, ca = (tid & 3) * 16;   // A-combine: 4 threads/row, 16 cols
    const int tok = m0 % NSEQ + ra;
    f32x4 acc[2][2] = {};

    // B staging via global_load_lds: wave w covers rows w*8..w*8+7 (512 shorts).
    // lane l: row offset l>>3, LDS block p=l&7 holds source block j=(l&7)^(l>>3).
    const int lrow = lane >> 3;
    const int jsw = (lane & 7) ^ lrow;
    const short* bBase = &Bt[(size_t)(n0 + wave * 8 + lrow) * DIM + jsw * 8];
    auto stageB = [&](int buf, int k0) {
        __builtin_amdgcn_global_load_lds(
            (const __attribute__((address_space(1))) unsigned int*)(bBase + k0),
            (__attribute__((address_space(3))) unsigned int*)&Bl[buf][wave * 512],
            16, 0, 0);
    };

    // A combine state (16 VGPRs staging)
    half8 a0, a1, a2, a3;
    float ls;
    auto loadA = [&](int h) {   // h = head = k-tile index
        const size_t pb = (size_t)(b * HEADS + h) * NSEQ + tok;
        const half8* o0 = reinterpret_cast<const half8*>(&op[pb * HD + ca]);
        const half8* o1 = reinterpret_cast<const half8*>(&op[(size_t)BH * NSEQ * HD + pb * HD + ca]);
        a0 = o0[0]; a1 = o0[1];
        a2 = o1[0]; a3 = o1[1];
        ls = lp[pb] + lp[(size_t)BH * NSEQ + pb];
    };
    auto storeA = [&](int buf) {
        const float inv = __builtin_amdgcn_rcpf(ls);
        short8v s0, s1;
#pragma unroll
        for (int j = 0; j < 8; ++j) {
            s0[j] = f2bf(((float)a0[j] + (float)a2[j]) * inv);
            s1[j] = f2bf(((float)a1[j] + (float)a3[j]) * inv);
        }
        *reinterpret_cast<short8v*>(&At[buf][ra * LDSP + ca]) = s0;
        *reinterpret_cast<short8v*>(&At[buf][ra * LDSP + ca + 8]) = s1;
    };

    // prologue: tile 0 (A combined to LDS, B DMA in flight)
    loadA(0);
    stageB(0, 0);
    storeA(0);

    const int rx = l16 & 7;
    int cur = 0;
    for (int t = 0; t < NKT; ++t) {
        __syncthreads();   // drains vmcnt(0): Bl[cur] complete; At[cur] writes visible
        const bool pre = (t + 1 < NKT);
        if (pre) {
            stageB(cur ^ 1, (t + 1) * 64);   // async DMA during compute
            loadA(t + 1);                    // A-part loads in flight during compute
        }
#pragma unroll
        for (int ks = 0; ks < 2; ++ks) {
            bf16x8 af[2], bf[2];
#pragma unroll
            for (int mt = 0; mt < 2; ++mt)
                af[mt] = *reinterpret_cast<const bf16x8*>(
                    &At[cur][(wm + mt * 16 + l16) * LDSP + ks * 32 + quad * 8]);
#pragma unroll
            for (int nt = 0; nt < 2; ++nt) {
                const int R = wn + nt * 16 + l16;
                bf[nt] = *reinterpret_cast<const bf16x8*>(
                    &Bl[cur][R * 64 + (((ks * 4 + quad) ^ rx) * 8)]);
            }
#pragma unroll
            for (int mt = 0; mt < 2; ++mt)
#pragma unroll
                for (int nt = 0; nt < 2; ++nt)
                    acc[mt][nt] = __builtin_amdgcn_mfma_f32_16x16x32_bf16(af[mt], bf[nt], acc[mt][nt], 0, 0, 0);
        }
        if (pre) storeA(cur ^ 1);   // combine waits on loads issued above (compute-phase latency)
        cur ^= 1;
    }

#pragma unroll
    for (int mt = 0; mt < 2; ++mt)
#pragma unroll
        for (int nt = 0; nt < 2; ++nt) {
            const int n = n0 + wn + nt * 16 + l16;
            const float bi = bias[n];
#pragma unroll
            for (int rg = 0; rg < 4; ++rg) {
                const int m = m0 + wm + mt * 16 + quad * 4 + rg;
                out[(size_t)m * DIM + n] = acc[mt][nt][rg] + bi;
            }
        }
}

extern "C" void kernel_launch(void* const* d_in, const int* in_sizes, int n_in,
                              void* d_out, int out_size, void* d_ws, size_t ws_size,
                              hipStream_t stream) {
    const float* x      = (const float*)d_in[0];
    const float* w_qkv  = (const float*)d_in[1];
    const float* b_qkv  = (const float*)d_in[2];
    const float* w_proj = (const float*)d_in[3];
    const float* b_proj = (const float*)d_in[4];
    float* out = (float*)d_out;

    short* xb     = (short*)d_ws;                         // 4608*768
    short* wqkvb  = xb + (size_t)M_TOK * DIM;             // 2304*768
    short* wprojb = wqkvb + (size_t)3 * DIM * DIM;        // 768*768
    short* qb     = wprojb + (size_t)DIM * DIM;           // 24*2304*64 bf16
    short* kb     = qb + (size_t)BH * NSEQ * HD;
    short* vtb    = kb + (size_t)BH * NSEQ * HD;          // f16 [bh,d,tok]
    short* opart  = vtb + (size_t)BH * NSEQ * HD;         // f16 [2,bh,row,d]
    float* lpart  = (float*)(opart + (size_t)2 * BH * NSEQ * HD); // f32 [2,bh,row]

    // merged converts (1 kernel)
    cvt_all_kernel<<<(CN1 + CN2 + CN3) / 256, 256, 0, stream>>>(
        x, w_qkv, w_proj, xb, wqkvb, wprojb);

    // qkv GEMM + bias + RoPE + QSCALE + scatter (3-buffer counted-vmcnt pipeline)
    dim3 g1(M_TOK / 128, 3 * DIM / 128);
    gemm_qkv_kernel<<<g1, 512, 0, stream>>>(xb, wqkvb, b_qkv, qb, kb, (_Float16*)vtb);

    // attention partials (key-split x2), 8 waves x 32 q-rows, XCD-swizzled 1D grid
    attn_kernel<<<dim3(9 * 2 * BH), 512, 0, stream>>>(qb, kb, (const _Float16*)vtb,
                                                      (_Float16*)opart, lpart);

    // proj GEMM v2 with fused combine+normalize (8 waves, 1 barrier/iter)
    gemm_proj_kernel<<<dim3(M_TOK / 128, DIM / 64), 512, 0, stream>>>(
        (const _Float16*)opart, lpart, wprojb, b_proj, out);
}